// Round 7
// baseline (484.122 us; speedup 1.0000x reference)
//
#include <hip/hip_runtime.h>

// Problem constants (from reference):
//   obj   : [1, 2048, 2048] fp32      (16.7 MB, L2/L3-resident)
//   waves : [4, 1024, 128, 128] fp32  (256 MB == L3 size)
//   pos   : [1024, 2] int32           values in [0,1920)
// Outputs (concatenated in d_out, fp32):
//   patches     : [1024, 1, 128, 128]
//   object_norm : [2048, 2048]
//
// R7: full-width strip gather. R6 post-mortem: patch rows are 512B-ALIGNED
// in waves, but tile-gathers read column sub-ranges -> unaligned partial-line
// segments (~1.5x line traffic) whose boundary re-reads thrash the exactly-
// waves-sized L3 -> waves HBM fetch ~380 MB instead of 256. Fix: gather unit
// = one 2048x2 object strip. Each covering patch contributes its ENTIRE
// 128-col row -> complete aligned-row reads; every waves line fetched exactly
// once device-wide (256 MB exact, L3-independent). The variable column
// offset is absorbed by accumulating into a 16 KB LDS strip with shared-mem
// atomicAdd (ds_add_f32, stride-1 conflict-free, 16.8M lane-atomics total --
// NOT the memory-side global atomics that killed R4). Strip flushed once as
// contiguous nontemporal float4. Crop blocks unchanged, interleaved 16:1.

#define NMODES 4
#define NB     1024
#define PH     128
#define PW     128
#define OH     2048
#define OW     2048

#define STRIPH  2                         // strip height (rows)
#define NSTRIP  (OH / STRIPH)             // 1024 gather blocks
#define NCROP   (NB * PH * PW / 4 / 256)  // 16384 crop blocks
#define NTOTAL  (NSTRIP + NCROP)          // 17408 = 17 * 1024
#define CAP     160                       // entries/strip: mean 64.5, +12 sigma

typedef float vfloat4 __attribute__((ext_vector_type(4)));

// ---------------------------------------------------------------------------
// Fused kernel. bid % 17 == 0 -> strip-gather block (1024); else crop block
// (16384). Interleave keeps the obj/patches stream and the waves/norm
// stream concurrently active.
// ---------------------------------------------------------------------------
__global__ __launch_bounds__(256) void fused_crop_norm(
    const float* __restrict__ obj,
    const float* __restrict__ waves,
    const int*   __restrict__ pos,
    float* __restrict__ patches,
    float* __restrict__ norm)
{
    const int bid = blockIdx.x;
    const int tid = threadIdx.x;

    __shared__ float s_strip[STRIPH * OW];   // 16 KB accumulation strip
    __shared__ int   s_cnt;
    __shared__ int   s_bb[CAP];              // b * PH*PW
    __shared__ int   s_r[CAP];
    __shared__ int   s_c[CAP];

    if (bid % 17 == 0) {
        // ============== gather: one 2048x2 strip of object_norm ===========
        const int g  = bid / 17;             // 0..1023
        const int Y0 = g * STRIPH;

        for (int i = tid; i < STRIPH * OW; i += 256) s_strip[i] = 0.0f;
        if (tid == 0) s_cnt = 0;
        __syncthreads();

        // --- self-binning: scan pos (8 KB, L2-hot), row-overlap test only ---
        for (int b = tid; b < NB; b += 256) {
            const int r0 = pos[2 * b];
            if ((r0 < Y0 + STRIPH) & (r0 + PH > Y0)) {
                const int i = atomicAdd(&s_cnt, 1);
                if (i < CAP) {
                    s_bb[i] = b * (PH * PW);
                    s_r[i]  = r0;
                    s_c[i]  = pos[2 * b + 1];
                }
            }
        }
        __syncthreads();
        const int count = min(s_cnt, CAP);

        const int row = tid >> 7;            // 0..1 (wave-uniform)
        const int col = tid & 127;           // 0..127
        const int Y   = Y0 + row;
        const int MS  = NB * PH * PW;        // mode stride in elements

        #pragma unroll 2
        for (int i = 0; i < count; ++i) {
            const int dr = Y - s_r[i];       // broadcast LDS read
            if ((unsigned)dr < (unsigned)PH) {   // wave-uniform branch
                // full 512B-aligned patch row: lanes 0..127 read cols 0..127
                const float* wp = waves + s_bb[i] + dr * PW + col;
                const float a0 = wp[0];
                const float a1 = wp[MS];
                const float a2 = wp[2 * MS];
                const float a3 = wp[3 * MS];
                const float s  = a0 * a0 + a1 * a1 + a2 * a2 + a3 * a3;
                // stride-1 shared atomics: ds_add_f32, conflict-free
                atomicAdd(&s_strip[row * OW + s_c[i] + col], s);
            }
        }
        __syncthreads();

        // --- flush strip: rows Y0, Y0+1 are contiguous in norm ---
        float* dst = norm + (size_t)Y0 * OW;
        for (int i = tid; i < STRIPH * OW / 4; i += 256) {
            const vfloat4 v = reinterpret_cast<const vfloat4*>(s_strip)[i];
            __builtin_nontemporal_store(v, reinterpret_cast<vfloat4*>(dst) + i);
        }
    } else {
        // =================== crop: one 256-quad chunk of patches ==========
        const int c     = bid - bid / 17 - 1;  // 0..16383
        const int q     = c * 256 + tid;
        const int b     = q >> 12;             // quads/batch = PH*PW/4
        const int local = q & 4095;
        const int h     = local >> 5;          // 32 quads per row
        const int w     = (local & 31) << 2;

        const int r0 = pos[b * 2 + 0];         // wave-uniform -> s_load
        const int c0 = pos[b * 2 + 1];

        const int oidx = (r0 + h) * OW + (c0 + w);
        vfloat4 p;
        p.x = obj[oidx + 0];
        p.y = obj[oidx + 1];
        p.z = obj[oidx + 2];
        p.w = obj[oidx + 3];
        // patches never re-read -> nontemporal 16B store
        __builtin_nontemporal_store(
            p, reinterpret_cast<vfloat4*>(patches + b * (PH * PW) + h * PW + w));
    }
}

extern "C" void kernel_launch(void* const* d_in, const int* in_sizes, int n_in,
                              void* d_out, int out_size, void* d_ws, size_t ws_size,
                              hipStream_t stream) {
    const float* obj   = (const float*)d_in[0];
    const float* waves = (const float*)d_in[1];
    const int*   pos   = (const int*)d_in[2];

    float* patches = (float*)d_out;                        // 16,777,216 elems
    float* norm    = (float*)d_out + (size_t)NB * PH * PW; // 4,194,304 elems

    // No workspace, no memset, one launch.
    fused_crop_norm<<<NTOTAL, 256, 0, stream>>>(obj, waves, pos,
                                                patches, norm);
}